// Round 5
// baseline (35842.270 us; speedup 1.0000x reference)
//
#include <hip/hip_runtime.h>

// Problem constants: B=512 T=512 I=128 H=512 C=128 OUT_T=128
#define Bq 512
#define Tq 512
#define Iq 128
#define Hq 512
#define Cq 128
#define OUT_Tq 128
#define Gq 4   // batches per block

// ---- workspace layout (BYTE offsets) ----
// wtE : 640*512 f16  [k>>3][n][k&7]   655360 B
// wt1 : 512*512 f16  [k>>3][n][k&7]   524288 B
// wt2 : 512*128 f16  [k>>3][c][k&7]   131072 B
// cb  : 512 f32                          2048 B
#define OFFB_WTE 0
#define OFFB_WT1 655360
#define OFFB_WT2 1179648
#define OFFB_CB  1310720

typedef _Float16 h2_t __attribute__((ext_vector_type(2)));

__device__ __forceinline__ float fdot2f(unsigned w, unsigned v, float c) {
#if __has_builtin(__builtin_amdgcn_fdot2)
    return __builtin_amdgcn_fdot2(__builtin_bit_cast(h2_t, w),
                                  __builtin_bit_cast(h2_t, v), c, false);
#else
    union { unsigned u; _Float16 h[2]; } A, B; A.u = w; B.u = v;
    return c + (float)A.h[0] * (float)B.h[0] + (float)A.h[1] * (float)B.h[1];
#endif
}

__global__ void prep_enc(const float* __restrict__ W_ih, const float* __restrict__ W_hh,
                         _Float16* __restrict__ wt) {
    int idx = blockIdx.x * 256 + threadIdx.x;           // over 512*640
    if (idx >= 512 * 640) return;
    int n = idx / 640, k = idx % 640;
    float v = (k < Iq) ? W_ih[n * Iq + k] : W_hh[n * Hq + (k - Iq)];
    wt[(((k >> 3) * 512) + n) * 8 + (k & 7)] = (_Float16)v;
}

__global__ void prep_fc1(const float* __restrict__ W, _Float16* __restrict__ wt) {
    int idx = blockIdx.x * 256 + threadIdx.x;           // over 512*512
    if (idx >= 512 * 512) return;
    int n = idx >> 9, k = idx & 511;
    wt[(((k >> 3) * 512) + n) * 8 + (k & 7)] = (_Float16)W[n * Hq + k];
}

__global__ void prep_fc2(const float* __restrict__ W, _Float16* __restrict__ wt) {
    int idx = blockIdx.x * 256 + threadIdx.x;           // over 128*512
    if (idx >= 128 * 512) return;
    int c = idx >> 9, k = idx & 511;
    wt[(((k >> 3) * 128) + c) * 8 + (k & 7)] = (_Float16)W[c * Hq + k];
}

__global__ void prep_bias(const float* __restrict__ bih, const float* __restrict__ bhh,
                          float* __restrict__ cb) {
    int n = blockIdx.x * 256 + threadIdx.x;
    if (n < Hq) cb[n] = bih[n] + bhh[n];
}

// 16 dot2s of one j-row against 4 batches
#define DOT16(W_, J_)                                                        \
    do {                                                                     \
        uint4 v0 = I4[(J_)];                                                 \
        uint4 v1 = I4[80 + (J_)];                                            \
        uint4 v2 = I4[160 + (J_)];                                           \
        uint4 v3 = I4[240 + (J_)];                                           \
        aA0 = fdot2f((W_).x, v0.x, aA0); aA0 = fdot2f((W_).y, v0.y, aA0);    \
        aB0 = fdot2f((W_).z, v0.z, aB0); aB0 = fdot2f((W_).w, v0.w, aB0);    \
        aA1 = fdot2f((W_).x, v1.x, aA1); aA1 = fdot2f((W_).y, v1.y, aA1);    \
        aB1 = fdot2f((W_).z, v1.z, aB1); aB1 = fdot2f((W_).w, v1.w, aB1);    \
        aA2 = fdot2f((W_).x, v2.x, aA2); aA2 = fdot2f((W_).y, v2.y, aA2);    \
        aB2 = fdot2f((W_).z, v2.z, aB2); aB2 = fdot2f((W_).w, v2.w, aB2);    \
        aA3 = fdot2f((W_).x, v3.x, aA3); aA3 = fdot2f((W_).y, v3.y, aA3);    \
        aB3 = fdot2f((W_).z, v3.z, aB3); aB3 = fdot2f((W_).w, v3.w, aB3);    \
    } while (0)

// R3 skeleton + register ping/pong pipeline sized to AVOID SPILL (R4 lesson):
// 4-row chunks -> wA[4]+wB[4] = 32 VGPRs; total live ~90 < 128 cap.
// 4 x dwordx4 per wave in flight per buffer; loads for chunk c+1 issue before
// chunk c's 64 dot2s. Clamped tail prefetch re-reads the last chunk (L2 hit).
__global__ void __launch_bounds__(512, 2)
rnn_fused(const float* __restrict__ x, const int* __restrict__ lengths,
          const uint4* __restrict__ WE, const uint4* __restrict__ W1,
          const uint4* __restrict__ W2, const float* __restrict__ cbias,
          const float* __restrict__ fc1_b, const float* __restrict__ fc2_b,
          float* __restrict__ out) {
    __shared__ __align__(16) unsigned in2_s[Gq][320];   // f16 pairs: [x(128) | h(512)]
    __shared__ __align__(16) unsigned mid2_s[Gq][256];  // f16 pairs: mid(512)

    const int tid = threadIdx.x;          // 0..511
    const int n = tid;
    const int gb0 = blockIdx.x * Gq;

    const int len0 = lengths[gb0 + 0];
    const int len1 = lengths[gb0 + 1];
    const int len2 = lengths[gb0 + 2];
    const int len3 = lengths[gb0 + 3];
    const int tmax = max(max(len0, len1), max(len2, len3));

    const float cb = cbias[n];
    _Float16* inh = (_Float16*)in2_s;     // [b*640 + k]

    // h = 0
    for (int b = 0; b < Gq; ++b) inh[b * 640 + 128 + n] = (_Float16)0.f;
    __syncthreads();

    const uint4* I4 = (const uint4*)in2_s;   // [b*80 + j], j = 8-k-elem chunk

    // ---------------- encoder ----------------
    for (int t = 0; t < tmax; ++t) {
        {   // stage x_t as f16 (4 batches x 128)
            int b = tid >> 7, i = tid & 127;
            inh[b * 640 + i] =
                (_Float16)x[(size_t)(gb0 + b) * Tq * Iq + (size_t)t * Iq + i];
        }
        __syncthreads();
        float aA0=0,aB0=0,aA1=0,aB1=0,aA2=0,aB2=0,aA3=0,aB3=0;
        uint4 wA[4], wB[4];
        {
            const uint4* wp = WE + n;
#pragma unroll
            for (int p = 0; p < 4; ++p) wA[p] = wp[p * 512];
        }
        // 20 chunks of 4 j-rows, 2 per iteration (ping/pong)
        for (int c = 0; c < 20; c += 2) {
            {   // prefetch chunk c+1 into wB
                const uint4* wp = WE + (c + 1) * 4 * 512 + n;
#pragma unroll
                for (int p = 0; p < 4; ++p) wB[p] = wp[p * 512];
            }
#pragma unroll
            for (int p = 0; p < 4; ++p) DOT16(wA[p], c * 4 + p);
            {   // prefetch chunk c+2 into wA (clamped at last iter)
                int c2 = (c + 2 < 20) ? c + 2 : 19;
                const uint4* wp = WE + c2 * 4 * 512 + n;
#pragma unroll
                for (int p = 0; p < 4; ++p) wA[p] = wp[p * 512];
            }
#pragma unroll
            for (int p = 0; p < 4; ++p) DOT16(wB[p], (c + 1) * 4 + p);
        }
        float nh0 = tanhf(aA0 + aB0 + cb);
        float nh1 = tanhf(aA1 + aB1 + cb);
        float nh2 = tanhf(aA2 + aB2 + cb);
        float nh3 = tanhf(aA3 + aB3 + cb);
        __syncthreads();    // all reads of in2_s done
        if (t < len0) inh[0 * 640 + 128 + n] = (_Float16)nh0;
        if (t < len1) inh[1 * 640 + 128 + n] = (_Float16)nh1;
        if (t < len2) inh[2 * 640 + 128 + n] = (_Float16)nh2;
        if (t < len3) inh[3 * 640 + 128 + n] = (_Float16)nh3;
        // next iter: x-stage writes disjoint region; top barrier publishes both
    }
    __syncthreads();

    // ---------------- decoder ----------------
    const float f1b = fc1_b[n];
    const int bq = tid >> 7, c = tid & 127;
    const float f2b = fc2_b[c];
    _Float16* midh = (_Float16*)mid2_s;      // [b*512 + n]
    const uint4* M4 = (const uint4*)mid2_s;  // [b*64 + j]
    const uint4* Wd = WE + 16 * 512;         // W_hh^T part (k = 128..639)

    for (int t = 0; t < OUT_Tq; ++t) {
        // P1: nh = tanh(cbias + h @ W_hh^T)   (64 j-rows, operands at I4[16+j])
        float aA0=0,aB0=0,aA1=0,aB1=0,aA2=0,aB2=0,aA3=0,aB3=0;
        uint4 wA[4], wB[4];
        {
            const uint4* wp = Wd + n;
#pragma unroll
            for (int p = 0; p < 4; ++p) wA[p] = wp[p * 512];
        }
        for (int cc = 0; cc < 16; cc += 2) {
            {
                const uint4* wp = Wd + (cc + 1) * 4 * 512 + n;
#pragma unroll
                for (int p = 0; p < 4; ++p) wB[p] = wp[p * 512];
            }
#pragma unroll
            for (int p = 0; p < 4; ++p) DOT16(wA[p], 16 + cc * 4 + p);
            {
                int c2 = (cc + 2 < 16) ? cc + 2 : 15;
                const uint4* wp = Wd + c2 * 4 * 512 + n;
#pragma unroll
                for (int p = 0; p < 4; ++p) wA[p] = wp[p * 512];
            }
#pragma unroll
            for (int p = 0; p < 4; ++p) DOT16(wB[p], 16 + (cc + 1) * 4 + p);
        }
        float nh0 = tanhf(aA0 + aB0 + cb);
        float nh1 = tanhf(aA1 + aB1 + cb);
        float nh2 = tanhf(aA2 + aB2 + cb);
        float nh3 = tanhf(aA3 + aB3 + cb);
        __syncthreads();    // P1 reads of h done
        inh[0 * 640 + 128 + n] = (_Float16)nh0;
        inh[1 * 640 + 128 + n] = (_Float16)nh1;
        inh[2 * 640 + 128 + n] = (_Float16)nh2;
        inh[3 * 640 + 128 + n] = (_Float16)nh3;
        __syncthreads();    // new h published
        // P2: mid = relu(nh @ fc1^T + fc1_b)
        aA0=0;aB0=0;aA1=0;aB1=0;aA2=0;aB2=0;aA3=0;aB3=0;
        {
            const uint4* wp = W1 + n;
#pragma unroll
            for (int p = 0; p < 4; ++p) wA[p] = wp[p * 512];
        }
        for (int cc = 0; cc < 16; cc += 2) {
            {
                const uint4* wp = W1 + (cc + 1) * 4 * 512 + n;
#pragma unroll
                for (int p = 0; p < 4; ++p) wB[p] = wp[p * 512];
            }
#pragma unroll
            for (int p = 0; p < 4; ++p) DOT16(wA[p], 16 + cc * 4 + p);
            {
                int c2 = (cc + 2 < 16) ? cc + 2 : 15;
                const uint4* wp = W1 + c2 * 4 * 512 + n;
#pragma unroll
                for (int p = 0; p < 4; ++p) wA[p] = wp[p * 512];
            }
#pragma unroll
            for (int p = 0; p < 4; ++p) DOT16(wB[p], 16 + (cc + 1) * 4 + p);
        }
        // prior iter's P3 mid-reads finished before its trailing barrier -> safe
        midh[0 * 512 + n] = (_Float16)fmaxf(aA0 + aB0 + f1b, 0.f);
        midh[1 * 512 + n] = (_Float16)fmaxf(aA1 + aB1 + f1b, 0.f);
        midh[2 * 512 + n] = (_Float16)fmaxf(aA2 + aB2 + f1b, 0.f);
        midh[3 * 512 + n] = (_Float16)fmaxf(aA3 + aB3 + f1b, 0.f);
        __syncthreads();    // mid published
        // P3: out = mid @ fc2^T + fc2_b   (thread -> (bq, c))
        float ao = 0.f, ao2 = 0.f;
        {
            const uint4* wp = W2 + c;
#pragma unroll
            for (int p = 0; p < 4; ++p) wA[p] = wp[p * 128];
        }
        for (int cc = 0; cc < 16; cc += 2) {
            {
                const uint4* wp = W2 + (cc + 1) * 4 * 128 + c;
#pragma unroll
                for (int p = 0; p < 4; ++p) wB[p] = wp[p * 128];
            }
#pragma unroll
            for (int p = 0; p < 4; ++p) {
                uint4 m = M4[bq * 64 + cc * 4 + p];
                ao  = fdot2f(wA[p].x, m.x, ao);  ao  = fdot2f(wA[p].y, m.y, ao);
                ao2 = fdot2f(wA[p].z, m.z, ao2); ao2 = fdot2f(wA[p].w, m.w, ao2);
            }
            {
                int c2 = (cc + 2 < 16) ? cc + 2 : 15;
                const uint4* wp = W2 + c2 * 4 * 128 + c;
#pragma unroll
                for (int p = 0; p < 4; ++p) wA[p] = wp[p * 128];
            }
#pragma unroll
            for (int p = 0; p < 4; ++p) {
                uint4 m = M4[bq * 64 + (cc + 1) * 4 + p];
                ao  = fdot2f(wB[p].x, m.x, ao);  ao  = fdot2f(wB[p].y, m.y, ao);
                ao2 = fdot2f(wB[p].z, m.z, ao2); ao2 = fdot2f(wB[p].w, m.w, ao2);
            }
        }
        out[((size_t)(gb0 + bq) * OUT_Tq + t) * Cq + c] = ao + ao2 + f2b;
        __syncthreads();    // mid reads done before next-iter writes
    }
}

extern "C" void kernel_launch(void* const* d_in, const int* in_sizes, int n_in,
                              void* d_out, int out_size, void* d_ws, size_t ws_size,
                              hipStream_t stream) {
    const float* x      = (const float*)d_in[0];
    const int*   lens   = (const int*)d_in[1];
    // d_in[2] = out_lengths (constant 128, hardcoded)
    const float* W_ih   = (const float*)d_in[3];
    const float* W_hh   = (const float*)d_in[4];
    const float* b_ih   = (const float*)d_in[5];
    const float* b_hh   = (const float*)d_in[6];
    const float* fc1_W  = (const float*)d_in[7];
    const float* fc1_b  = (const float*)d_in[8];
    const float* fc2_W  = (const float*)d_in[9];
    const float* fc2_b  = (const float*)d_in[10];

    char* wsb = (char*)d_ws;
    _Float16* wtE = (_Float16*)(wsb + OFFB_WTE);
    _Float16* wt1 = (_Float16*)(wsb + OFFB_WT1);
    _Float16* wt2 = (_Float16*)(wsb + OFFB_WT2);
    float*    cb  = (float*)   (wsb + OFFB_CB);

    prep_enc <<<1280, 256, 0, stream>>>(W_ih, W_hh, wtE);
    prep_fc1 <<<1024, 256, 0, stream>>>(fc1_W, wt1);
    prep_fc2 <<< 256, 256, 0, stream>>>(fc2_W, wt2);
    prep_bias<<<   2, 256, 0, stream>>>(b_ih, b_hh, cb);

    rnn_fused<<<Bq / Gq, 512, 0, stream>>>(x, lens,
                                           (const uint4*)wtE, (const uint4*)wt1,
                                           (const uint4*)wt2, cb,
                                           fc1_b, fc2_b, (float*)d_out);
}

// Round 6
// 30309.747 us; speedup vs baseline: 1.1825x; 1.1825x over previous
//
#include <hip/hip_runtime.h>

// Problem constants: B=512 T=512 I=128 H=512 C=128 OUT_T=128
#define Bq 512
#define Tq 512
#define Iq 128
#define Hq 512
#define Cq 128
#define OUT_Tq 128
#define Gq 4   // batches per block

// ---- workspace layout (BYTE offsets) ----
// wtE : 640*512 f16  [k>>3][n][k&7]   655360 B
// wt1 : 512*512 f16  [k>>3][n][k&7]   524288 B
// wt2 : 512*128 f16  [k>>3][c][k&7]   131072 B
// cb  : 512 f32                          2048 B
#define OFFB_WTE 0
#define OFFB_WT1 655360
#define OFFB_WT2 1179648
#define OFFB_CB  1310720

typedef _Float16 h2_t __attribute__((ext_vector_type(2)));

__device__ __forceinline__ float fdot2f(unsigned w, unsigned v, float c) {
#if __has_builtin(__builtin_amdgcn_fdot2)
    return __builtin_amdgcn_fdot2(__builtin_bit_cast(h2_t, w),
                                  __builtin_bit_cast(h2_t, v), c, false);
#else
    union { unsigned u; _Float16 h[2]; } A, B; A.u = w; B.u = v;
    return c + (float)A.h[0] * (float)B.h[0] + (float)A.h[1] * (float)B.h[1];
#endif
}

__global__ void prep_enc(const float* __restrict__ W_ih, const float* __restrict__ W_hh,
                         _Float16* __restrict__ wt) {
    int idx = blockIdx.x * 256 + threadIdx.x;           // over 512*640
    if (idx >= 512 * 640) return;
    int n = idx / 640, k = idx % 640;
    float v = (k < Iq) ? W_ih[n * Iq + k] : W_hh[n * Hq + (k - Iq)];
    wt[(((k >> 3) * 512) + n) * 8 + (k & 7)] = (_Float16)v;
}

__global__ void prep_fc1(const float* __restrict__ W, _Float16* __restrict__ wt) {
    int idx = blockIdx.x * 256 + threadIdx.x;           // over 512*512
    if (idx >= 512 * 512) return;
    int n = idx >> 9, k = idx & 511;
    wt[(((k >> 3) * 512) + n) * 8 + (k & 7)] = (_Float16)W[n * Hq + k];
}

__global__ void prep_fc2(const float* __restrict__ W, _Float16* __restrict__ wt) {
    int idx = blockIdx.x * 256 + threadIdx.x;           // over 128*512
    if (idx >= 128 * 512) return;
    int c = idx >> 9, k = idx & 511;
    wt[(((k >> 3) * 128) + c) * 8 + (k & 7)] = (_Float16)W[c * Hq + k];
}

__global__ void prep_bias(const float* __restrict__ bih, const float* __restrict__ bhh,
                          float* __restrict__ cb) {
    int n = blockIdx.x * 256 + threadIdx.x;
    if (n < Hq) cb[n] = bih[n] + bhh[n];
}

// 16 dot2s of one j-row against 4 batches
#define DOT16(W_, J_)                                                        \
    do {                                                                     \
        uint4 v0 = I4[(J_)];                                                 \
        uint4 v1 = I4[80 + (J_)];                                            \
        uint4 v2 = I4[160 + (J_)];                                           \
        uint4 v3 = I4[240 + (J_)];                                           \
        aA0 = fdot2f((W_).x, v0.x, aA0); aA0 = fdot2f((W_).y, v0.y, aA0);    \
        aB0 = fdot2f((W_).z, v0.z, aB0); aB0 = fdot2f((W_).w, v0.w, aB0);    \
        aA1 = fdot2f((W_).x, v1.x, aA1); aA1 = fdot2f((W_).y, v1.y, aA1);    \
        aB1 = fdot2f((W_).z, v1.z, aB1); aB1 = fdot2f((W_).w, v1.w, aB1);    \
        aA2 = fdot2f((W_).x, v2.x, aA2); aA2 = fdot2f((W_).y, v2.y, aA2);    \
        aB2 = fdot2f((W_).z, v2.z, aB2); aB2 = fdot2f((W_).w, v2.w, aB2);    \
        aA3 = fdot2f((W_).x, v3.x, aA3); aA3 = fdot2f((W_).y, v3.y, aA3);    \
        aB3 = fdot2f((W_).z, v3.z, aB3); aB3 = fdot2f((W_).w, v3.w, aB3);    \
    } while (0)

// R4 pipeline, UNCAPPED registers (R5 lesson): grid=128 blocks on 256 CUs
// means exactly 1 block/CU -- a 2-blocks/CU launch bound only strangled the
// register allocator (128 cap -> scratch spill, 17 GB of scratch traffic).
// __launch_bounds__(512) alone = 8 waves/block = 2 waves/SIMD = 256-VGPR
// budget at the SAME occupancy we actually run. wA[8]/wB[8] ping-pong keeps
// 8 KB/wave of weight loads in flight under every compute window.
__global__ void __launch_bounds__(512)
rnn_fused(const float* __restrict__ x, const int* __restrict__ lengths,
          const uint4* __restrict__ WE, const uint4* __restrict__ W1,
          const uint4* __restrict__ W2, const float* __restrict__ cbias,
          const float* __restrict__ fc1_b, const float* __restrict__ fc2_b,
          float* __restrict__ out) {
    __shared__ __align__(16) unsigned in2_s[Gq][320];   // f16 pairs: [x(128) | h(512)]
    __shared__ __align__(16) unsigned mid2_s[Gq][256];  // f16 pairs: mid(512)

    const int tid = threadIdx.x;          // 0..511
    const int n = tid;
    const int gb0 = blockIdx.x * Gq;

    const int len0 = lengths[gb0 + 0];
    const int len1 = lengths[gb0 + 1];
    const int len2 = lengths[gb0 + 2];
    const int len3 = lengths[gb0 + 3];
    const int tmax = max(max(len0, len1), max(len2, len3));

    const float cb = cbias[n];
    _Float16* inh = (_Float16*)in2_s;     // [b*640 + k]

    // h = 0
    for (int b = 0; b < Gq; ++b) inh[b * 640 + 128 + n] = (_Float16)0.f;
    __syncthreads();

    const uint4* I4 = (const uint4*)in2_s;   // [b*80 + j], j = 8-k-elem chunk

    // ---------------- encoder ----------------
    for (int t = 0; t < tmax; ++t) {
        {   // stage x_t as f16 (4 batches x 128)
            int b = tid >> 7, i = tid & 127;
            inh[b * 640 + i] =
                (_Float16)x[(size_t)(gb0 + b) * Tq * Iq + (size_t)t * Iq + i];
        }
        __syncthreads();
        float aA0=0,aB0=0,aA1=0,aB1=0,aA2=0,aB2=0,aA3=0,aB3=0;
        uint4 wA[8], wB[8];
        {
            const uint4* wp = WE + n;
#pragma unroll
            for (int p = 0; p < 8; ++p) wA[p] = wp[p * 512];
        }
        // 10 chunks of 8 j-rows, processed 2 per iteration (ping/pong)
        for (int c = 0; c < 10; c += 2) {
            {   // prefetch chunk c+1 into wB
                const uint4* wp = WE + (c + 1) * 8 * 512 + n;
#pragma unroll
                for (int p = 0; p < 8; ++p) wB[p] = wp[p * 512];
            }
#pragma unroll
            for (int p = 0; p < 8; ++p) DOT16(wA[p], c * 8 + p);
            {   // prefetch chunk c+2 into wA (clamped: last iter reloads chunk 9)
                int c2 = (c + 2 < 10) ? c + 2 : 9;
                const uint4* wp = WE + c2 * 8 * 512 + n;
#pragma unroll
                for (int p = 0; p < 8; ++p) wA[p] = wp[p * 512];
            }
#pragma unroll
            for (int p = 0; p < 8; ++p) DOT16(wB[p], (c + 1) * 8 + p);
        }
        float nh0 = tanhf(aA0 + aB0 + cb);
        float nh1 = tanhf(aA1 + aB1 + cb);
        float nh2 = tanhf(aA2 + aB2 + cb);
        float nh3 = tanhf(aA3 + aB3 + cb);
        __syncthreads();    // all reads of in2_s done
        if (t < len0) inh[0 * 640 + 128 + n] = (_Float16)nh0;
        if (t < len1) inh[1 * 640 + 128 + n] = (_Float16)nh1;
        if (t < len2) inh[2 * 640 + 128 + n] = (_Float16)nh2;
        if (t < len3) inh[3 * 640 + 128 + n] = (_Float16)nh3;
        // next iter: x-stage writes disjoint region; top barrier publishes both
    }
    __syncthreads();

    // ---------------- decoder ----------------
    const float f1b = fc1_b[n];
    const int bq = tid >> 7, c = tid & 127;
    const float f2b = fc2_b[c];
    _Float16* midh = (_Float16*)mid2_s;      // [b*512 + n]
    const uint4* M4 = (const uint4*)mid2_s;  // [b*64 + j]
    const uint4* Wd = WE + 16 * 512;         // W_hh^T part (k = 128..639)

    for (int t = 0; t < OUT_Tq; ++t) {
        // P1: nh = tanh(cbias + h @ W_hh^T)   (64 j-rows, operands at I4[16+j])
        float aA0=0,aB0=0,aA1=0,aB1=0,aA2=0,aB2=0,aA3=0,aB3=0;
        uint4 wA[8], wB[8];
        {
            const uint4* wp = Wd + n;
#pragma unroll
            for (int p = 0; p < 8; ++p) wA[p] = wp[p * 512];
        }
        for (int cc = 0; cc < 8; cc += 2) {
            {
                const uint4* wp = Wd + (cc + 1) * 8 * 512 + n;
#pragma unroll
                for (int p = 0; p < 8; ++p) wB[p] = wp[p * 512];
            }
#pragma unroll
            for (int p = 0; p < 8; ++p) DOT16(wA[p], 16 + cc * 8 + p);
            {
                int c2 = (cc + 2 < 8) ? cc + 2 : 7;
                const uint4* wp = Wd + c2 * 8 * 512 + n;
#pragma unroll
                for (int p = 0; p < 8; ++p) wA[p] = wp[p * 512];
            }
#pragma unroll
            for (int p = 0; p < 8; ++p) DOT16(wB[p], 16 + (cc + 1) * 8 + p);
        }
        float nh0 = tanhf(aA0 + aB0 + cb);
        float nh1 = tanhf(aA1 + aB1 + cb);
        float nh2 = tanhf(aA2 + aB2 + cb);
        float nh3 = tanhf(aA3 + aB3 + cb);
        __syncthreads();    // P1 reads of h done
        inh[0 * 640 + 128 + n] = (_Float16)nh0;
        inh[1 * 640 + 128 + n] = (_Float16)nh1;
        inh[2 * 640 + 128 + n] = (_Float16)nh2;
        inh[3 * 640 + 128 + n] = (_Float16)nh3;
        __syncthreads();    // new h published
        // P2: mid = relu(nh @ fc1^T + fc1_b)
        aA0=0;aB0=0;aA1=0;aB1=0;aA2=0;aB2=0;aA3=0;aB3=0;
        {
            const uint4* wp = W1 + n;
#pragma unroll
            for (int p = 0; p < 8; ++p) wA[p] = wp[p * 512];
        }
        for (int cc = 0; cc < 8; cc += 2) {
            {
                const uint4* wp = W1 + (cc + 1) * 8 * 512 + n;
#pragma unroll
                for (int p = 0; p < 8; ++p) wB[p] = wp[p * 512];
            }
#pragma unroll
            for (int p = 0; p < 8; ++p) DOT16(wA[p], 16 + cc * 8 + p);
            {
                int c2 = (cc + 2 < 8) ? cc + 2 : 7;
                const uint4* wp = W1 + c2 * 8 * 512 + n;
#pragma unroll
                for (int p = 0; p < 8; ++p) wA[p] = wp[p * 512];
            }
#pragma unroll
            for (int p = 0; p < 8; ++p) DOT16(wB[p], 16 + (cc + 1) * 8 + p);
        }
        // prior iter's P3 mid-reads finished before its trailing barrier -> safe
        midh[0 * 512 + n] = (_Float16)fmaxf(aA0 + aB0 + f1b, 0.f);
        midh[1 * 512 + n] = (_Float16)fmaxf(aA1 + aB1 + f1b, 0.f);
        midh[2 * 512 + n] = (_Float16)fmaxf(aA2 + aB2 + f1b, 0.f);
        midh[3 * 512 + n] = (_Float16)fmaxf(aA3 + aB3 + f1b, 0.f);
        __syncthreads();    // mid published
        // P3: out = mid @ fc2^T + fc2_b   (thread -> (bq, c))
        float ao = 0.f, ao2 = 0.f;
        {
            const uint4* wp = W2 + c;
#pragma unroll
            for (int p = 0; p < 8; ++p) wA[p] = wp[p * 128];
        }
        for (int cc = 0; cc < 8; cc += 2) {
            {
                const uint4* wp = W2 + (cc + 1) * 8 * 128 + c;
#pragma unroll
                for (int p = 0; p < 8; ++p) wB[p] = wp[p * 128];
            }
#pragma unroll
            for (int p = 0; p < 8; ++p) {
                uint4 m = M4[bq * 64 + cc * 8 + p];
                ao  = fdot2f(wA[p].x, m.x, ao);  ao  = fdot2f(wA[p].y, m.y, ao);
                ao2 = fdot2f(wA[p].z, m.z, ao2); ao2 = fdot2f(wA[p].w, m.w, ao2);
            }
            {
                int c2 = (cc + 2 < 8) ? cc + 2 : 7;
                const uint4* wp = W2 + c2 * 8 * 128 + c;
#pragma unroll
                for (int p = 0; p < 8; ++p) wA[p] = wp[p * 128];
            }
#pragma unroll
            for (int p = 0; p < 8; ++p) {
                uint4 m = M4[bq * 64 + (cc + 1) * 8 + p];
                ao  = fdot2f(wB[p].x, m.x, ao);  ao  = fdot2f(wB[p].y, m.y, ao);
                ao2 = fdot2f(wB[p].z, m.z, ao2); ao2 = fdot2f(wB[p].w, m.w, ao2);
            }
        }
        out[((size_t)(gb0 + bq) * OUT_Tq + t) * Cq + c] = ao + ao2 + f2b;
        __syncthreads();    // mid reads done before next-iter writes
    }
}

extern "C" void kernel_launch(void* const* d_in, const int* in_sizes, int n_in,
                              void* d_out, int out_size, void* d_ws, size_t ws_size,
                              hipStream_t stream) {
    const float* x      = (const float*)d_in[0];
    const int*   lens   = (const int*)d_in[1];
    // d_in[2] = out_lengths (constant 128, hardcoded)
    const float* W_ih   = (const float*)d_in[3];
    const float* W_hh   = (const float*)d_in[4];
    const float* b_ih   = (const float*)d_in[5];
    const float* b_hh   = (const float*)d_in[6];
    const float* fc1_W  = (const float*)d_in[7];
    const float* fc1_b  = (const float*)d_in[8];
    const float* fc2_W  = (const float*)d_in[9];
    const float* fc2_b  = (const float*)d_in[10];

    char* wsb = (char*)d_ws;
    _Float16* wtE = (_Float16*)(wsb + OFFB_WTE);
    _Float16* wt1 = (_Float16*)(wsb + OFFB_WT1);
    _Float16* wt2 = (_Float16*)(wsb + OFFB_WT2);
    float*    cb  = (float*)   (wsb + OFFB_CB);

    prep_enc <<<1280, 256, 0, stream>>>(W_ih, W_hh, wtE);
    prep_fc1 <<<1024, 256, 0, stream>>>(fc1_W, wt1);
    prep_fc2 <<< 256, 256, 0, stream>>>(fc2_W, wt2);
    prep_bias<<<   2, 256, 0, stream>>>(b_ih, b_hh, cb);

    rnn_fused<<<Bq / Gq, 512, 0, stream>>>(x, lens,
                                           (const uint4*)wtE, (const uint4*)wt1,
                                           (const uint4*)wt2, cb,
                                           fc1_b, fc2_b, (float*)d_out);
}